// Round 1
// baseline (190.969 us; speedup 1.0000x reference)
//
#include <hip/hip_runtime.h>
#include <hip/hip_bf16.h>

// Problem constants (fixed by reference)
#define Bb 8
#define Nn 8192
#define Cc 128
#define Hh 8
#define DHd 64
#define Gg 32
#define HD 512            // H*DH
#define KSPLIT 64         // encode K-split blocks per batch
#define NCHUNK 128        // n per encode block (8192/64)
#define LN_EPS 1e-5f

typedef __attribute__((ext_vector_type(8))) short short8v;
typedef __attribute__((ext_vector_type(4))) float f32x4;

__device__ __forceinline__ short f2bf(float f) {
  __hip_bfloat16 h = __float2bfloat16(f);   // RNE
  return __builtin_bit_cast(short, h);
}

// ---------------------------------------------------------------------------
// K1: encode partials. Y_p[b][ks][g][c] = sum_{n in chunk} inv_in[n,g]*x[b,n,c]
// Also sg_p[ks][g] = sum_n inv_in[n,g] (b==0 blocks only) for the b_in term.
// inv_in is head-broadcast -> use head 0 slice.
// ---------------------------------------------------------------------------
__global__ void __launch_bounds__(256) k_encode(const float* __restrict__ x,
                                                const float* __restrict__ inv_in,
                                                float* __restrict__ yp,
                                                float* __restrict__ sgp) {
  int blk = blockIdx.x;          // 0..511
  int b = blk >> 6;
  int ks = blk & 63;
  int nb = ks * NCHUNK;
  int t = threadIdx.x;
  int c = t & 127;
  int g0 = (t >> 7) << 4;                       // 0 or 16, wave-uniform
  g0 = __builtin_amdgcn_readfirstlane(g0);      // force SGPR -> s_load path
  const float* __restrict__ xp = x + ((size_t)b * Nn + nb) * Cc + c;
  const float* __restrict__ ip = inv_in + (size_t)nb * Gg + g0;
  float acc[16];
#pragma unroll
  for (int j = 0; j < 16; ++j) acc[j] = 0.f;
#pragma unroll 4
  for (int n = 0; n < NCHUNK; ++n) {
    float xv = xp[(size_t)n * Cc];
    const float* iv = ip + n * Gg;              // wave-uniform address
#pragma unroll
    for (int j = 0; j < 16; ++j) acc[j] = fmaf(xv, iv[j], acc[j]);
  }
  float* ypp = yp + (size_t)blk * (Gg * Cc) + (size_t)g0 * Cc + c;
#pragma unroll
  for (int j = 0; j < 16; ++j) ypp[(size_t)j * Cc] = acc[j];

  if (b == 0 && t < Gg) {   // basis column sums (for b_in term)
    float s = 0.f;
    const float* ip2 = inv_in + (size_t)nb * Gg + t;
    for (int n = 0; n < NCHUNK; ++n) s += ip2[(size_t)n * Gg];
    sgp[ks * Gg + t] = s;
  }
}

// ---------------------------------------------------------------------------
// K2: reduce partials. Y[b][g][c] = sum_ks Y_p ; Sg[g] = sum_ks sg_p
// ---------------------------------------------------------------------------
__global__ void __launch_bounds__(256) k_reduce(const float* __restrict__ yp,
                                                const float* __restrict__ sgp,
                                                float* __restrict__ Y,
                                                float* __restrict__ Sg) {
  int blk = blockIdx.x;
  if (blk < 128) {
    int b = blk >> 4;
    int off = (blk & 15) * 256 + threadIdx.x;   // 0..4095
    const float* p = yp + (size_t)b * KSPLIT * (Gg * Cc) + off;
    float s = 0.f;
#pragma unroll 4
    for (int ks = 0; ks < KSPLIT; ++ks) s += p[(size_t)ks * (Gg * Cc)];
    Y[(size_t)b * (Gg * Cc) + off] = s;
  } else {
    if (threadIdx.x < Gg) {
      float s = 0.f;
      for (int ks = 0; ks < KSPLIT; ++ks) s += sgp[ks * Gg + threadIdx.x];
      Sg[threadIdx.x] = s;
    }
  }
}

// ---------------------------------------------------------------------------
// K3: per-(b,h): spec = Y@W_in + Sg*b_in ; LayerNorm over (G,DH) ; @mlp_w
// writes spec2[b][g][h*64+dh]  (so K4 reads a contiguous 512-vector per (b,g))
// ---------------------------------------------------------------------------
__global__ void __launch_bounds__(256) k_mid1(const float* __restrict__ Y,
                                              const float* __restrict__ Sg,
                                              const float* __restrict__ W_in,
                                              const float* __restrict__ b_in,
                                              const float* __restrict__ ln_g,
                                              const float* __restrict__ ln_b,
                                              const float* __restrict__ mlp_w,
                                              float* __restrict__ spec2) {
  int b = blockIdx.x >> 3, h = blockIdx.x & 7;
  int t = threadIdx.x;
  __shared__ float Ys[Gg][Cc + 1];
  __shared__ float sn[Gg][DHd + 1];
  __shared__ float rsum[4], rsum2[4];

  for (int i = t; i < Gg * Cc; i += 256) Ys[i >> 7][i & 127] = Y[(size_t)b * Gg * Cc + i];
  __syncthreads();

  int g = t >> 3;
  int d0 = (t & 7) * 8;
  float acc[8];
#pragma unroll
  for (int j = 0; j < 8; ++j) acc[j] = 0.f;
  const float* wp = W_in + h * DHd + d0;
  for (int cc = 0; cc < Cc; ++cc) {
    float yv = Ys[g][cc];
    const float* w = wp + (size_t)cc * HD;
#pragma unroll
    for (int j = 0; j < 8; ++j) acc[j] = fmaf(yv, w[j], acc[j]);
  }
  float sgv = Sg[g];
#pragma unroll
  for (int j = 0; j < 8; ++j) acc[j] = fmaf(sgv, b_in[h * DHd + d0 + j], acc[j]);

  // LayerNorm over all 2048 values held by the block
  float s = 0.f, s2 = 0.f;
#pragma unroll
  for (int j = 0; j < 8; ++j) { s += acc[j]; s2 += acc[j] * acc[j]; }
  for (int off = 32; off; off >>= 1) {
    s += __shfl_down(s, off);
    s2 += __shfl_down(s2, off);
  }
  int w64 = t >> 6, l = t & 63;
  if (l == 0) { rsum[w64] = s; rsum2[w64] = s2; }
  __syncthreads();
  float ts = 0.f, ts2 = 0.f;
#pragma unroll
  for (int i = 0; i < 4; ++i) { ts += rsum[i]; ts2 += rsum2[i]; }
  float mu = ts * (1.f / 2048.f);
  float var = ts2 * (1.f / 2048.f) - mu * mu;
  float rs = rsqrtf(var + LN_EPS);
#pragma unroll
  for (int j = 0; j < 8; ++j) {
    float v = (acc[j] - mu) * rs;
    v = v * ln_g[g * DHd + d0 + j] + ln_b[g * DHd + d0 + j];
    sn[g][d0 + j] = v;
  }
  __syncthreads();

  // per-head channel mix: spec2[g][o] = sum_i sn[g][i] * mlp_w[i][o]
  float m[8];
#pragma unroll
  for (int j = 0; j < 8; ++j) m[j] = 0.f;
  for (int i = 0; i < DHd; ++i) {
    float sv = sn[g][i];
    const float* mw = mlp_w + (size_t)i * DHd + d0;
#pragma unroll
    for (int j = 0; j < 8; ++j) m[j] = fmaf(sv, mw[j], m[j]);
  }
  float* sp = spec2 + ((size_t)b * Gg + g) * HD + h * DHd + d0;
#pragma unroll
  for (int j = 0; j < 8; ++j) sp[j] = m[j];
}

// ---------------------------------------------------------------------------
// K4: T[b,g,c] = sum_{hd} spec2[b,g,hd]*W_out[hd,c]; store transposed bf16
// Tt[b][c][g] so decode's B(A)-fragments are contiguous 16B loads.
// ---------------------------------------------------------------------------
__global__ void __launch_bounds__(128) k_mid2(const float* __restrict__ spec2,
                                              const float* __restrict__ W_out,
                                              __hip_bfloat16* __restrict__ Tt) {
  int b = blockIdx.x >> 5, g = blockIdx.x & 31;
  int c = threadIdx.x;
  __shared__ float s2[HD];
  for (int i = c; i < HD; i += 128) s2[i] = spec2[((size_t)b * Gg + g) * HD + i];
  __syncthreads();
  float acc = 0.f;
#pragma unroll 8
  for (int k = 0; k < HD; ++k) acc = fmaf(s2[k], W_out[(size_t)k * Cc + c], acc);
  Tt[((size_t)b * Cc + c) * Gg + g] = __float2bfloat16(acc);
}

// ---------------------------------------------------------------------------
// K5: decode. out[b,n,c] = sum_g inv_out[n,g]*T[b,g,c] + b_out[c]
// MFMA 16x16x32 with A = Tt (c x g), B = inv_out^T (g x n) so the C-layout
// gives each lane 4 consecutive c -> float4 stores (64B-dense segments).
// ---------------------------------------------------------------------------
__global__ void __launch_bounds__(256) k_decode(const __hip_bfloat16* __restrict__ Tt,
                                                const float* __restrict__ inv_out,
                                                const float* __restrict__ b_out,
                                                float* __restrict__ out) {
  int blk = blockIdx.x;            // 512
  int b = blk >> 6;
  int nb = (blk & 63) * 128;
  int t = threadIdx.x, w = t >> 6, l = t & 63;
  int lo = l & 15, hi = l >> 4;

  // A-fragments: 8 c-tiles of T^t, loaded once per block (L2-hot, 8KB/batch)
  const __hip_bfloat16* tb = Tt + (size_t)b * Cc * Gg;
  short8v a[8];
#pragma unroll
  for (int ct = 0; ct < 8; ++ct)
    a[ct] = *reinterpret_cast<const short8v*>(tb + ((size_t)(ct * 16 + lo)) * Gg + hi * 8);
  float4 bo[8];
#pragma unroll
  for (int ct = 0; ct < 8; ++ct)
    bo[ct] = *reinterpret_cast<const float4*>(b_out + ct * 16 + hi * 4);

#pragma unroll
  for (int sIdx = 0; sIdx < 2; ++sIdx) {
    int n0 = nb + (w * 2 + sIdx) * 16;
    const float* ipn = inv_out + (size_t)(n0 + lo) * Gg + hi * 8;
    float4 f0 = *reinterpret_cast<const float4*>(ipn);
    float4 f1 = *reinterpret_cast<const float4*>(ipn + 4);
    short8v bf;
    bf[0] = f2bf(f0.x); bf[1] = f2bf(f0.y); bf[2] = f2bf(f0.z); bf[3] = f2bf(f0.w);
    bf[4] = f2bf(f1.x); bf[5] = f2bf(f1.y); bf[6] = f2bf(f1.z); bf[7] = f2bf(f1.w);

#pragma unroll
    for (int ct = 0; ct < 8; ++ct) {
      f32x4 z = {0.f, 0.f, 0.f, 0.f};
      f32x4 d = __builtin_amdgcn_mfma_f32_16x16x32_bf16(a[ct], bf, z, 0, 0, 0);
      float4 r;
      r.x = d[0] + bo[ct].x;
      r.y = d[1] + bo[ct].y;
      r.z = d[2] + bo[ct].z;
      r.w = d[3] + bo[ct].w;
      size_t idx = ((size_t)b * Nn + n0 + lo) * Cc + ct * 16 + hi * 4;
      *reinterpret_cast<float4*>(out + idx) = r;
    }
  }
}

// ---------------------------------------------------------------------------
extern "C" void kernel_launch(void* const* d_in, const int* in_sizes, int n_in,
                              void* d_out, int out_size, void* d_ws, size_t ws_size,
                              hipStream_t stream) {
  const float* x      = (const float*)d_in[0];
  const float* W_in   = (const float*)d_in[1];
  const float* b_in   = (const float*)d_in[2];
  const float* mlp_w  = (const float*)d_in[3];
  const float* ln_g   = (const float*)d_in[4];
  const float* ln_b   = (const float*)d_in[5];
  const float* W_out  = (const float*)d_in[6];
  const float* b_out  = (const float*)d_in[7];
  const float* inv_in = (const float*)d_in[8];   // (H,N,G) head-broadcast -> head 0
  const float* inv_out= (const float*)d_in[9];
  float* out = (float*)d_out;

  char* ws = (char*)d_ws;
  float* yp    = (float*)(ws);                        // 512*4096 f32 = 8 MB
  float* sgp   = (float*)(ws + 8388608);              // 64*32 f32
  float* Y     = (float*)(ws + 8396800);              // 8*32*128 f32
  float* Sg    = (float*)(ws + 8527872);              // 32 f32
  float* spec2 = (float*)(ws + 8528000);              // 8*32*512 f32
  __hip_bfloat16* Tt = (__hip_bfloat16*)(ws + 9052288); // 8*128*32 bf16

  k_encode<<<dim3(512), dim3(256), 0, stream>>>(x, inv_in, yp, sgp);
  k_reduce<<<dim3(129), dim3(256), 0, stream>>>(yp, sgp, Y, Sg);
  k_mid1<<<dim3(64), dim3(256), 0, stream>>>(Y, Sg, W_in, b_in, ln_g, ln_b, mlp_w, spec2);
  k_mid2<<<dim3(256), dim3(128), 0, stream>>>(spec2, W_out, Tt);
  k_decode<<<dim3(512), dim3(256), 0, stream>>>(Tt, inv_out, b_out, out);
}

// Round 2
// 151.453 us; speedup vs baseline: 1.2609x; 1.2609x over previous
//
#include <hip/hip_runtime.h>
#include <hip/hip_bf16.h>

// Problem constants (fixed by reference)
#define Bb 8
#define Nn 8192
#define Cc 128
#define Hh 8
#define DHd 64
#define Gg 32
#define HD 512            // H*DH
#define KSPLIT 64         // encode K-split blocks per batch
#define NCHUNK 128        // n per encode block (8192/64)
#define LN_EPS 1e-5f

typedef __attribute__((ext_vector_type(8))) short short8v;
typedef __attribute__((ext_vector_type(4))) short short4v;
typedef __attribute__((ext_vector_type(4))) float f32x4;

__device__ __forceinline__ short f2bf(float f) {
  __hip_bfloat16 h = __float2bfloat16(f);   // RNE
  return __builtin_bit_cast(short, h);
}

// ---------------------------------------------------------------------------
// K1: encode partials. Y_p[b][ks][g][c] = sum_{n in chunk} inv_in[n,g]*x[b,n,c]
// 512 threads: (c = t&127, g-octet = t>>7) -> 8 acc/thread, 4 waves/SIMD.
// Also sg_p[ks][g] = sum_n inv_in[n,g] (b==0 blocks) for the b_in term.
// ---------------------------------------------------------------------------
__global__ void __launch_bounds__(512) k_encode(const float* __restrict__ x,
                                                const float* __restrict__ inv_in,
                                                float* __restrict__ yp,
                                                float* __restrict__ sgp) {
  int blk = blockIdx.x;          // 0..511
  int b = blk >> 6;
  int ks = blk & 63;
  int nb = ks * NCHUNK;
  int t = threadIdx.x;
  int c = t & 127;
  int g0 = (t >> 7) << 3;                       // 0,8,16,24 wave-uniform
  g0 = __builtin_amdgcn_readfirstlane(g0);      // force SGPR -> s_load path
  const float* __restrict__ xp = x + ((size_t)b * Nn + nb) * Cc + c;
  const float* __restrict__ ip = inv_in + (size_t)nb * Gg + g0;
  float acc[8];
#pragma unroll
  for (int j = 0; j < 8; ++j) acc[j] = 0.f;
#pragma unroll 4
  for (int n = 0; n < NCHUNK; ++n) {
    float xv = xp[(size_t)n * Cc];
    const float* iv = ip + n * Gg;              // wave-uniform address
#pragma unroll
    for (int j = 0; j < 8; ++j) acc[j] = fmaf(xv, iv[j], acc[j]);
  }
  float* ypp = yp + (size_t)blk * (Gg * Cc) + (size_t)g0 * Cc + c;
#pragma unroll
  for (int j = 0; j < 8; ++j) ypp[(size_t)j * Cc] = acc[j];

  if (b == 0 && t < Gg) {   // basis column sums (for b_in term)
    float s = 0.f;
    const float* ip2 = inv_in + (size_t)nb * Gg + t;
    for (int n = 0; n < NCHUNK; ++n) s += ip2[(size_t)n * Gg];
    sgp[ks * Gg + t] = s;
  }
}

// ---------------------------------------------------------------------------
// K2: reduce partials (blk<128), Sg (blk==128), and W_out cast+transpose to
// bf16 W_ot[c][k] (blk 129..160) for the MFMA in K4.
// ---------------------------------------------------------------------------
__global__ void __launch_bounds__(256) k_reduce(const float* __restrict__ yp,
                                                const float* __restrict__ sgp,
                                                const float* __restrict__ W_out,
                                                float* __restrict__ Y,
                                                float* __restrict__ Sg,
                                                __hip_bfloat16* __restrict__ W_ot) {
  int blk = blockIdx.x;
  int t = threadIdx.x;
  if (blk < 128) {
    int b = blk >> 4;
    int off = (blk & 15) * 256 + t;             // 0..4095
    const float* p = yp + (size_t)b * KSPLIT * (Gg * Cc) + off;
    float s = 0.f;
#pragma unroll 4
    for (int ks = 0; ks < KSPLIT; ++ks) s += p[(size_t)ks * (Gg * Cc)];
    Y[(size_t)b * (Gg * Cc) + off] = s;
  } else if (blk == 128) {
    if (t < Gg) {
      float s = 0.f;
      for (int ks = 0; ks < KSPLIT; ++ks) s += sgp[ks * Gg + t];
      Sg[t] = s;
    }
  } else {
    // cast+transpose 16 k-rows of W_out (512x128 f32) into W_ot (128x512 bf16)
    int kb = (blk - 129) * 16;
    __shared__ float tile[16][132];
    int kk = t >> 7, c = t & 127;
#pragma unroll
    for (int p = 0; p < 8; ++p)
      tile[p * 2 + kk][c] = W_out[(size_t)(kb + p * 2 + kk) * Cc + c];
    __syncthreads();
    int c2 = t >> 1, kh = (t & 1) * 8;
    short8v o;
#pragma unroll
    for (int j = 0; j < 8; ++j) o[j] = f2bf(tile[kh + j][c2]);
    *reinterpret_cast<short8v*>(W_ot + (size_t)c2 * HD + kb + kh) = o;
  }
}

// ---------------------------------------------------------------------------
// K3: per-(b,h): spec = Y@W_in + Sg*b_in ; LayerNorm over (G,DH) ; @mlp_w
// W_in h-slice and mlp_w staged in LDS. Writes spec2 as bf16 [b][g][h*64+dh].
// ---------------------------------------------------------------------------
__global__ void __launch_bounds__(256) k_mid1(const float* __restrict__ Y,
                                              const float* __restrict__ Sg,
                                              const float* __restrict__ W_in,
                                              const float* __restrict__ b_in,
                                              const float* __restrict__ ln_g,
                                              const float* __restrict__ ln_b,
                                              const float* __restrict__ mlp_w,
                                              __hip_bfloat16* __restrict__ spec2b) {
  int b = blockIdx.x >> 3, h = blockIdx.x & 7;
  int t = threadIdx.x;
  __shared__ float Ys[Gg][Cc + 1];
  __shared__ float Wl[Cc][DHd];     // W_in h-slice, later mlp_w (64x64)
  __shared__ float sn[Gg][DHd + 1];
  __shared__ float rsum[4], rsum2[4];

  for (int i = t; i < Gg * Cc; i += 256) Ys[i >> 7][i & 127] = Y[(size_t)b * Gg * Cc + i];
  for (int i = t; i < Cc * DHd; i += 256)
    Wl[i >> 6][i & 63] = W_in[(size_t)(i >> 6) * HD + h * DHd + (i & 63)];
  __syncthreads();

  int g = t >> 3;
  int d0 = (t & 7) * 8;
  float acc[8];
#pragma unroll
  for (int j = 0; j < 8; ++j) acc[j] = 0.f;
  for (int cc = 0; cc < Cc; ++cc) {
    float yv = Ys[g][cc];
#pragma unroll
    for (int j = 0; j < 8; ++j) acc[j] = fmaf(yv, Wl[cc][d0 + j], acc[j]);
  }
  float sgv = Sg[g];
#pragma unroll
  for (int j = 0; j < 8; ++j) acc[j] = fmaf(sgv, b_in[h * DHd + d0 + j], acc[j]);

  // LayerNorm over all 2048 values held by the block
  float s = 0.f, s2 = 0.f;
#pragma unroll
  for (int j = 0; j < 8; ++j) { s += acc[j]; s2 += acc[j] * acc[j]; }
  for (int off = 32; off; off >>= 1) {
    s += __shfl_down(s, off);
    s2 += __shfl_down(s2, off);
  }
  int w64 = t >> 6, l = t & 63;
  if (l == 0) { rsum[w64] = s; rsum2[w64] = s2; }
  __syncthreads();
  float ts = 0.f, ts2 = 0.f;
#pragma unroll
  for (int i = 0; i < 4; ++i) { ts += rsum[i]; ts2 += rsum2[i]; }
  float mu = ts * (1.f / 2048.f);
  float var = ts2 * (1.f / 2048.f) - mu * mu;
  float rs = rsqrtf(var + LN_EPS);
#pragma unroll
  for (int j = 0; j < 8; ++j) {
    float v = (acc[j] - mu) * rs;
    v = v * ln_g[g * DHd + d0 + j] + ln_b[g * DHd + d0 + j];
    sn[g][d0 + j] = v;
  }
  __syncthreads();
  // stage mlp_w (64x64) into Wl (safe: spec loop done before LN syncs)
  for (int i = t; i < DHd * DHd; i += 256) Wl[i >> 6][i & 63] = mlp_w[i];
  __syncthreads();

  // per-head channel mix: spec2[g][o] = sum_i sn[g][i] * mlp_w[i][o]
  float m[8];
#pragma unroll
  for (int j = 0; j < 8; ++j) m[j] = 0.f;
  for (int i = 0; i < DHd; ++i) {
    float sv = sn[g][i];
#pragma unroll
    for (int j = 0; j < 8; ++j) m[j] = fmaf(sv, Wl[i][d0 + j], m[j]);
  }
  short8v o;
#pragma unroll
  for (int j = 0; j < 8; ++j) o[j] = f2bf(m[j]);
  *reinterpret_cast<short8v*>((__hip_bfloat16*)spec2b + ((size_t)b * Gg + g) * HD + h * DHd + d0) = o;
}

// ---------------------------------------------------------------------------
// K4: T[b,g,c] = sum_k spec2[b,g,k]*W_out[k,c] via MFMA 16x16x32 bf16.
// A = spec2 (M=g), B = W_ot (N=c). D: col(lane&15)=c, row((lane>>4)*4+j)=g.
// Stores Tt[b][c][g] bf16 directly (decode's A-frag layout).
// 64 blocks = 8 b x 8 c-tiles; 2 waves = 2 g-tiles.
// ---------------------------------------------------------------------------
__global__ void __launch_bounds__(128) k_mid2(const __hip_bfloat16* __restrict__ spec2b,
                                              const __hip_bfloat16* __restrict__ W_ot,
                                              __hip_bfloat16* __restrict__ Tt) {
  int b = blockIdx.x >> 3, c0 = (blockIdx.x & 7) * 16;
  int t = threadIdx.x;
  int wt = t >> 6, l = t & 63;
  int l15 = l & 15, hi = l >> 4;
  const __hip_bfloat16* ap = spec2b + ((size_t)(b * Gg + wt * 16 + l15)) * HD + hi * 8;
  const __hip_bfloat16* bp = W_ot + ((size_t)(c0 + l15)) * HD + hi * 8;
  f32x4 acc = {0.f, 0.f, 0.f, 0.f};
#pragma unroll
  for (int kk = 0; kk < 16; ++kk) {
    short8v a = *reinterpret_cast<const short8v*>(ap + kk * 32);
    short8v bb = *reinterpret_cast<const short8v*>(bp + kk * 32);
    acc = __builtin_amdgcn_mfma_f32_16x16x32_bf16(a, bb, acc, 0, 0, 0);
  }
  short4v o;
#pragma unroll
  for (int j = 0; j < 4; ++j) o[j] = f2bf(acc[j]);
  *reinterpret_cast<short4v*>(Tt + ((size_t)(b * Cc + c0 + l15)) * Gg + wt * 16 + hi * 4) = o;
}

// ---------------------------------------------------------------------------
// K5: decode. out[b,n,c] = sum_g inv_out[n,g]*T[b,g,c] + b_out[c]
// ---------------------------------------------------------------------------
__global__ void __launch_bounds__(256) k_decode(const __hip_bfloat16* __restrict__ Tt,
                                                const float* __restrict__ inv_out,
                                                const float* __restrict__ b_out,
                                                float* __restrict__ out) {
  int blk = blockIdx.x;            // 512
  int b = blk >> 6;
  int nb = (blk & 63) * 128;
  int t = threadIdx.x, w = t >> 6, l = t & 63;
  int lo = l & 15, hi = l >> 4;

  const __hip_bfloat16* tb = Tt + (size_t)b * Cc * Gg;
  short8v a[8];
#pragma unroll
  for (int ct = 0; ct < 8; ++ct)
    a[ct] = *reinterpret_cast<const short8v*>(tb + ((size_t)(ct * 16 + lo)) * Gg + hi * 8);
  float4 bo[8];
#pragma unroll
  for (int ct = 0; ct < 8; ++ct)
    bo[ct] = *reinterpret_cast<const float4*>(b_out + ct * 16 + hi * 4);

#pragma unroll
  for (int sIdx = 0; sIdx < 2; ++sIdx) {
    int n0 = nb + (w * 2 + sIdx) * 16;
    const float* ipn = inv_out + (size_t)(n0 + lo) * Gg + hi * 8;
    float4 f0 = *reinterpret_cast<const float4*>(ipn);
    float4 f1 = *reinterpret_cast<const float4*>(ipn + 4);
    short8v bf;
    bf[0] = f2bf(f0.x); bf[1] = f2bf(f0.y); bf[2] = f2bf(f0.z); bf[3] = f2bf(f0.w);
    bf[4] = f2bf(f1.x); bf[5] = f2bf(f1.y); bf[6] = f2bf(f1.z); bf[7] = f2bf(f1.w);

#pragma unroll
    for (int ct = 0; ct < 8; ++ct) {
      f32x4 z = {0.f, 0.f, 0.f, 0.f};
      f32x4 d = __builtin_amdgcn_mfma_f32_16x16x32_bf16(a[ct], bf, z, 0, 0, 0);
      float4 r;
      r.x = d[0] + bo[ct].x;
      r.y = d[1] + bo[ct].y;
      r.z = d[2] + bo[ct].z;
      r.w = d[3] + bo[ct].w;
      size_t idx = ((size_t)b * Nn + n0 + lo) * Cc + ct * 16 + hi * 4;
      *reinterpret_cast<float4*>(out + idx) = r;
    }
  }
}

// ---------------------------------------------------------------------------
extern "C" void kernel_launch(void* const* d_in, const int* in_sizes, int n_in,
                              void* d_out, int out_size, void* d_ws, size_t ws_size,
                              hipStream_t stream) {
  const float* x      = (const float*)d_in[0];
  const float* W_in   = (const float*)d_in[1];
  const float* b_in   = (const float*)d_in[2];
  const float* mlp_w  = (const float*)d_in[3];
  const float* ln_g   = (const float*)d_in[4];
  const float* ln_b   = (const float*)d_in[5];
  const float* W_out  = (const float*)d_in[6];
  const float* b_out  = (const float*)d_in[7];
  const float* inv_in = (const float*)d_in[8];   // (H,N,G) head-broadcast -> head 0
  const float* inv_out= (const float*)d_in[9];
  float* out = (float*)d_out;

  char* ws = (char*)d_ws;
  float* yp    = (float*)(ws);                         // 512*4096 f32 = 8 MB
  float* sgp   = (float*)(ws + 8388608);               // 64*32 f32
  float* Y     = (float*)(ws + 8396800);               // 8*32*128 f32 (128 KB)
  float* Sg    = (float*)(ws + 8527872);               // 32 f32
  __hip_bfloat16* spec2b = (__hip_bfloat16*)(ws + 8528128); // 8*32*512 bf16 (256 KB)
  __hip_bfloat16* W_ot   = (__hip_bfloat16*)(ws + 8790272); // 128*512 bf16 (128 KB)
  __hip_bfloat16* Tt     = (__hip_bfloat16*)(ws + 8921344); // 8*128*32 bf16 (64 KB)

  k_encode<<<dim3(512), dim3(512), 0, stream>>>(x, inv_in, yp, sgp);
  k_reduce<<<dim3(161), dim3(256), 0, stream>>>(yp, sgp, W_out, Y, Sg, W_ot);
  k_mid1<<<dim3(64), dim3(256), 0, stream>>>(Y, Sg, W_in, b_in, ln_g, ln_b, mlp_w, spec2b);
  k_mid2<<<dim3(64), dim3(128), 0, stream>>>(spec2b, W_ot, Tt);
  k_decode<<<dim3(512), dim3(256), 0, stream>>>(Tt, inv_out, b_out, out);
}